// Round 3
// baseline (2482.800 us; speedup 1.0000x reference)
//
#include <hip/hip_runtime.h>

typedef unsigned short u16;
typedef unsigned int u32;
typedef __bf16 bf16x8 __attribute__((ext_vector_type(8)));
typedef float f32x4 __attribute__((ext_vector_type(4)));

__device__ __forceinline__ float bf2f(u16 h) {
  union { u32 u; float f; } c; c.u = ((u32)h) << 16; return c.f;
}
__device__ __forceinline__ float bflo(u32 u) {
  union { u32 u; float f; } c; c.u = u << 16; return c.f;
}
__device__ __forceinline__ float bfhi(u32 u) {
  union { u32 u; float f; } c; c.u = u & 0xffff0000u; return c.f;
}
// compiler emits packed v_cvt_pk_bf16_f32 for __bf16 casts (RNE)
__device__ __forceinline__ u32 pack2bf(float a, float b) {
  union { __bf16 h[2]; u32 u; } c; c.h[0] = (__bf16)a; c.h[1] = (__bf16)b;
  return c.u;
}
__device__ __forceinline__ u16 f2bf(float f) {
  union { __bf16 h; u16 u; } c; c.h = (__bf16)f; return c.u;
}

// Convert a weight slice W[n, col0 + k] (f32, row stride src_stride) into
// bf16 [N][Kd] zero-padded along K.
__global__ __launch_bounds__(256) void cvt_w(const float* __restrict__ src,
                                             u16* __restrict__ dst, int N,
                                             int Ks, int Kd, int src_stride,
                                             int col0) {
  int i = blockIdx.x * 256 + threadIdx.x;
  if (i >= N * Kd) return;
  int n = i / Kd, k = i % Kd;
  float v = (k < Ks) ? src[(size_t)n * src_stride + col0 + k] : 0.f;
  dst[i] = f2bf(v);
}

// Persistent 2-phase pipelined GEMM: C[M,256] = A[M,KPAD] * W[256,KPAD]^T.
// BM=32, BN=256, 4 waves (each 32x64). Grid-stride over M-tiles with
// double-buffered LDS A; B read from global (L2-resident weights).
// ASRC: 0 = A from f32 global [M][lda] (k<Kreal guard, converted)
//       1 = A from bf16 global [M][KPAD]
//       2 = A row r = bf16( Ab[idx1[r]] - Ab2[idx2[r]] )
// EPI:  0 = bf16 acc -> outb0, bf16 relu(acc) -> outb1
//       1 = v=acc+bias[c]; bf16 v -> outb0; relu(v) f32 -> outf
//       2 = v=acc+bf2f(addb[idx]); bf16 relu(v) -> outb1
//       3 = v=acc+bf2f(addb[idx]); relu(v) f32 -> outf
// M must be a multiple of 32.
template <int ASRC, int EPI, int KPAD>
__global__ __launch_bounds__(256, 4) void gemm3(
    const float* __restrict__ Af, int lda, int Kreal,
    const u16* __restrict__ Ab, const u16* __restrict__ Ab2,
    const int* __restrict__ idx1, const int* __restrict__ idx2,
    const u16* __restrict__ Bw,
    const u16* __restrict__ addb, const float* __restrict__ bias,
    u16* __restrict__ outb0, u16* __restrict__ outb1,
    float* __restrict__ outf, int ntiles) {
  constexpr int LDK = KPAD + 8;  // 16B-slot stride ≡ 1 (mod 8): rows spread banks
  __shared__ u16 As[2][32 * LDK];

  const int tid = threadIdx.x;
  const int lane = tid & 63, wid = tid >> 6;
  const int wn = wid * 64;
  const int stride = gridDim.x;

  // staging registers (live across the compute phase)
  float sf[ASRC == 0 ? KPAD / 8 : 1];
  uint4 sva[ASRC >= 1 ? KPAD / 64 : 1];
  uint4 svb[ASRC == 2 ? KPAD / 64 : 1];

  auto ISSUE = [&](int t) {
    int m0 = t * 32;
    if constexpr (ASRC == 0) {
#pragma unroll
      for (int p = 0; p < KPAD / 16; ++p) {
        int pi = p * 256 + tid;
        int row = pi / (KPAD / 2), kp = pi % (KPAD / 2);
        int k0 = kp * 2;
        const float* src = Af + (size_t)(m0 + row) * lda;
        sf[2 * p] = (k0 < Kreal) ? src[k0] : 0.f;
        sf[2 * p + 1] = (k0 + 1 < Kreal) ? src[k0 + 1] : 0.f;
      }
    } else if constexpr (ASRC == 1) {
#pragma unroll
      for (int p = 0; p < KPAD / 64; ++p) {
        int ch = p * 256 + tid;
        sva[p] = *reinterpret_cast<const uint4*>(Ab + (size_t)m0 * KPAD + (size_t)ch * 8);
      }
    } else {
      int row = tid >> 3, part = tid & 7;
      int gr = m0 + row;
      int r1 = idx1[gr], r2 = idx2[gr];
      const u16* pa = Ab + (size_t)r1 * KPAD + part * (KPAD / 8);
      const u16* pb = Ab2 + (size_t)r2 * KPAD + part * (KPAD / 8);
#pragma unroll
      for (int p = 0; p < KPAD / 64; ++p) {
        sva[p] = *reinterpret_cast<const uint4*>(pa + p * 8);
        svb[p] = *reinterpret_cast<const uint4*>(pb + p * 8);
      }
    }
  };

  auto WRITE = [&](int buf) {
    u16* dst = As[buf];
    if constexpr (ASRC == 0) {
#pragma unroll
      for (int p = 0; p < KPAD / 16; ++p) {
        int pi = p * 256 + tid;
        int row = pi / (KPAD / 2), kp = pi % (KPAD / 2);
        *reinterpret_cast<u32*>(&dst[row * LDK + kp * 2]) =
            pack2bf(sf[2 * p], sf[2 * p + 1]);
      }
    } else if constexpr (ASRC == 1) {
#pragma unroll
      for (int p = 0; p < KPAD / 64; ++p) {
        int ch = p * 256 + tid;
        int row = ch / (KPAD / 8), c8 = ch % (KPAD / 8);
        *reinterpret_cast<uint4*>(&dst[row * LDK + c8 * 8]) = sva[p];
      }
    } else {
      int row = tid >> 3, part = tid & 7;
#pragma unroll
      for (int p = 0; p < KPAD / 64; ++p) {
        uint4 va = sva[p], vb = svb[p], v;
        v.x = pack2bf(bflo(va.x) - bflo(vb.x), bfhi(va.x) - bfhi(vb.x));
        v.y = pack2bf(bflo(va.y) - bflo(vb.y), bfhi(va.y) - bfhi(vb.y));
        v.z = pack2bf(bflo(va.z) - bflo(vb.z), bfhi(va.z) - bfhi(vb.z));
        v.w = pack2bf(bflo(va.w) - bflo(vb.w), bfhi(va.w) - bfhi(vb.w));
        *reinterpret_cast<uint4*>(&dst[row * LDK + part * (KPAD / 8) + p * 8]) = v;
      }
    }
  };

  f32x4 acc[2][4];
  const int ar = lane & 15, ak = (lane >> 4) * 8;
  const int er = (lane >> 4) * 4, ec = lane & 15;

  float bv[4];
  if constexpr (EPI == 1) {
#pragma unroll
    for (int j = 0; j < 4; ++j) bv[j] = bias[wn + j * 16 + ec];
  }

  int tile = blockIdx.x;
  ISSUE(tile);
  WRITE(0);
  __syncthreads();
  int cur = 0;

  while (true) {
    int nxt = tile + stride;
    bool hn = nxt < ntiles;
    if (hn) ISSUE(nxt);

#pragma unroll
    for (int i = 0; i < 2; ++i)
#pragma unroll
      for (int j = 0; j < 4; ++j) acc[i][j] = (f32x4)(0.f);

    const u16* asb = As[cur];
#pragma unroll
    for (int kk = 0; kk < KPAD; kk += 32) {
      bf16x8 a0 = *reinterpret_cast<const bf16x8*>(&asb[ar * LDK + kk + ak]);
      bf16x8 a1 = *reinterpret_cast<const bf16x8*>(&asb[(16 + ar) * LDK + kk + ak]);
#pragma unroll
      for (int j = 0; j < 4; ++j) {
        bf16x8 b = *reinterpret_cast<const bf16x8*>(
            Bw + (size_t)(wn + j * 16 + ar) * KPAD + kk + ak);
        acc[0][j] = __builtin_amdgcn_mfma_f32_16x16x32_bf16(a0, b, acc[0][j], 0, 0, 0);
        acc[1][j] = __builtin_amdgcn_mfma_f32_16x16x32_bf16(a1, b, acc[1][j], 0, 0, 0);
      }
    }

    if (hn) WRITE(cur ^ 1);

    int m0 = tile * 32;
#pragma unroll
    for (int i = 0; i < 2; ++i) {
#pragma unroll
      for (int j = 0; j < 4; ++j) {
        int c = wn + j * 16 + ec;
#pragma unroll
        for (int q = 0; q < 4; ++q) {
          int r = m0 + i * 16 + er + q;
          size_t idx = (size_t)r * 256 + c;
          float v = acc[i][j][q];
          if (EPI == 0) {
            outb0[idx] = f2bf(v);
            outb1[idx] = f2bf(v > 0.f ? v : 0.f);
          } else if (EPI == 1) {
            v += bv[j];
            outb0[idx] = f2bf(v);
            outf[idx] = v > 0.f ? v : 0.f;
          } else if (EPI == 2) {
            v += bf2f(addb[idx]);
            outb1[idx] = f2bf(v > 0.f ? v : 0.f);
          } else {
            v += bf2f(addb[idx]);
            outf[idx] = v > 0.f ? v : 0.f;
          }
        }
      }
    }

    if (!hn) break;
    __syncthreads();
    tile = nxt;
    cur ^= 1;
  }
}

// a_msg[a][:] = sum_j msg[a2b[a][j]][:]  (bf16 in/out, f32 accum)
__global__ __launch_bounds__(256) void gather_sum(const u16* __restrict__ msg,
                                                  const int* __restrict__ a2b,
                                                  u16* __restrict__ amsg,
                                                  int n_atoms) {
  int wave = threadIdx.x >> 6, lane = threadIdx.x & 63;
  int atom = blockIdx.x * 4 + wave;
  if (atom >= n_atoms) return;
  float s0 = 0.f, s1 = 0.f, s2 = 0.f, s3 = 0.f;
  int base = atom * 6;
#pragma unroll
  for (int j = 0; j < 6; ++j) {
    int b = a2b[base + j];
    ushort4 v = *reinterpret_cast<const ushort4*>(msg + (size_t)b * 256 + lane * 4);
    s0 += bf2f(v.x);
    s1 += bf2f(v.y);
    s2 += bf2f(v.z);
    s3 += bf2f(v.w);
  }
  uint2 o;
  o.x = pack2bf(s0, s1);
  o.y = pack2bf(s2, s3);
  *reinterpret_cast<uint2*>(amsg + (size_t)atom * 256 + lane * 4) = o;
}

__global__ __launch_bounds__(256) void mol_mean(const float* __restrict__ dfin,
                                                float* __restrict__ out) {
  int mol = blockIdx.x, c = threadIdx.x;
  const float* p = dfin + (size_t)mol * (42 * 256) + c;
  float s = 0.f;
#pragma unroll
  for (int a = 0; a < 42; ++a) s += p[a * 256];
  out[(size_t)mol * 256 + c] = s * (1.0f / 42.0f);
}

extern "C" void kernel_launch(void* const* d_in, const int* in_sizes, int n_in,
                              void* d_out, int out_size, void* d_ws,
                              size_t ws_size, hipStream_t stream) {
  const float* f_atoms = (const float*)d_in[0];
  const float* f_bonds = (const float*)d_in[1];
  const float* W_i = (const float*)d_in[2];
  const float* W_h = (const float*)d_in[3];
  const float* W_o = (const float*)d_in[4];
  const float* b_o = (const float*)d_in[5];
  const int* a2b = (const int*)d_in[6];
  const int* b2a = (const int*)d_in[7];
  const int* b2revb = (const int*)d_in[8];

  const int NA = 168000, NB = 360000, H = 256;
  const size_t SZ_BH = (size_t)NB * H * 2;
  const size_t SZ_AH = (size_t)NA * H * 2;

  char* ws = (char*)d_ws;
  u16* inp_b = (u16*)ws;  ws += SZ_BH;
  u16* msgA  = (u16*)ws;  ws += SZ_BH;
  u16* msgB  = (u16*)ws;  ws += SZ_BH;
  u16* amsg  = (u16*)ws;  ws += SZ_AH;
  u16* base_b = (u16*)ws; ws += SZ_AH;
  u16* Wi_b  = (u16*)ws;  ws += 256 * 192 * 2;
  u16* Wh_b  = (u16*)ws;  ws += 256 * 256 * 2;
  u16* Wo1_b = (u16*)ws;  ws += 256 * 192 * 2;
  u16* Wo2_b = (u16*)ws;  ws += 256 * 256 * 2;

  float* out = (float*)d_out;
  float* d0 = out;
  float* d1 = d0 + (size_t)NA * H;
  float* d2 = d1 + (size_t)NA * H;
  float* dfin = d2 + (size_t)NA * H;
  float* mol = dfin + (size_t)NA * H;

  dim3 blk(256);
  cvt_w<<<dim3((256 * 192 + 255) / 256), blk, 0, stream>>>(W_i, Wi_b, 256, 147, 192, 147, 0);
  cvt_w<<<dim3((256 * 256 + 255) / 256), blk, 0, stream>>>(W_h, Wh_b, 256, 256, 256, 256, 0);
  cvt_w<<<dim3((256 * 192 + 255) / 256), blk, 0, stream>>>(W_o, Wo1_b, 256, 133, 192, 389, 0);
  cvt_w<<<dim3((256 * 256 + 255) / 256), blk, 0, stream>>>(W_o, Wo2_b, 256, 256, 256, 389, 133);

  const int GRID = 1024;
  int ntB = NB / 32;  // 11250
  int ntA = NA / 32;  // 5250

  // inp = f_bonds @ W_i^T ; msgA = relu(inp)
  gemm3<0, 0, 192><<<dim3(GRID), blk, 0, stream>>>(
      f_bonds, 147, 147, nullptr, nullptr, nullptr, nullptr, Wi_b, nullptr,
      nullptr, inp_b, msgA, nullptr, ntB);
  // base = f_atoms @ W_o1^T + b_o ; d0 = relu(base)
  gemm3<0, 1, 192><<<dim3(GRID), blk, 0, stream>>>(
      f_atoms, 133, 133, nullptr, nullptr, nullptr, nullptr, Wo1_b, nullptr,
      b_o, base_b, nullptr, d0, ntA);

  u16* mcur = msgA;
  u16* mnext = msgB;
  float* douts[3] = {d1, d2, dfin};
  for (int d = 0; d < 3; ++d) {
    gather_sum<<<dim3(NA / 4), blk, 0, stream>>>(mcur, a2b, amsg, NA);
    // d_{d+1} = relu(base + amsg @ W_o2^T)
    gemm3<1, 3, 256><<<dim3(GRID), blk, 0, stream>>>(
        nullptr, 0, 0, amsg, nullptr, nullptr, nullptr, Wo2_b, base_b, nullptr,
        nullptr, nullptr, douts[d], ntA);
    if (d < 2) {
      // msg' = relu(inp + (amsg[b2a] - msg[b2revb]) @ W_h^T)
      gemm3<2, 2, 256><<<dim3(GRID), blk, 0, stream>>>(
          nullptr, 0, 0, amsg, mcur, b2a, b2revb, Wh_b, inp_b, nullptr, nullptr,
          mnext, nullptr, ntB);
      u16* t = mcur; mcur = mnext; mnext = t;
    }
  }
  mol_mean<<<dim3(4000), blk, 0, stream>>>(dfin, mol);
}

// Round 5
// 2065.061 us; speedup vs baseline: 1.2023x; 1.2023x over previous
//
#include <hip/hip_runtime.h>

typedef unsigned short u16;
typedef unsigned int u32;
typedef __bf16 bf16x8 __attribute__((ext_vector_type(8)));
typedef float f32x4 __attribute__((ext_vector_type(4)));

__device__ __forceinline__ float bf2f(u16 h) {
  union { u32 u; float f; } c; c.u = ((u32)h) << 16; return c.f;
}
__device__ __forceinline__ float bflo(u32 u) {
  union { u32 u; float f; } c; c.u = u << 16; return c.f;
}
__device__ __forceinline__ float bfhi(u32 u) {
  union { u32 u; float f; } c; c.u = u & 0xffff0000u; return c.f;
}
// compiler emits packed v_cvt_pk_bf16_f32 for __bf16 casts (RNE)
__device__ __forceinline__ u32 pack2bf(float a, float b) {
  union { __bf16 h[2]; u32 u; } c; c.h[0] = (__bf16)a; c.h[1] = (__bf16)b;
  return c.u;
}
__device__ __forceinline__ u16 f2bf(float f) {
  union { __bf16 h; u16 u; } c; c.h = (__bf16)f; return c.u;
}

// Convert a weight slice W[n, col0 + k] (f32, row stride src_stride) into
// bf16 [N][Kd] zero-padded along K.
__global__ __launch_bounds__(256) void cvt_w(const float* __restrict__ src,
                                             u16* __restrict__ dst, int N,
                                             int Ks, int Kd, int src_stride,
                                             int col0) {
  int i = blockIdx.x * 256 + threadIdx.x;
  if (i >= N * Kd) return;
  int n = i / Kd, k = i % Kd;
  float v = (k < Ks) ? src[(size_t)n * src_stride + col0 + k] : 0.f;
  dst[i] = f2bf(v);
}

// All-register GEMM, no LDS, no barriers. C[M,256] = A[M,K] * W[256,K]^T.
// One 32x256 tile per block; 4 waves, wave = 32 rows x 64-col band.
// Swapped-operand MFMA: acc = mfma(w_frag, a_frag) -> lane holds 4
// consecutive output COLUMNS (n = wn + jw*16 + (lane>>4)*4 + q) at row
// m = m0 + im*16 + (lane&15). Stores: bf16 = 8B uint2, f32 = 16B float4.
// NOTE: output buffers must NOT alias A — waves of a block read the full
// K-row while other waves store their column band (no barrier): WAR race
// if in-place (round-4 bug).
// ASRC: 0 = A from f32 global [M][Kreal] (guarded, converted)
//       1 = A from bf16 global [M][KPAD]
// EPI:  0 = bf16 acc -> outb0
//       1 = v=acc+bias[c]; bf16 v -> outb0; relu(v) f32 -> outf
//       2 = v=acc+bf2f(addb[idx]); bf16 v -> outb0   (pre-activation store)
//       3 = v=acc+bf2f(addb[idx]); relu(v) f32 -> outf
template <int ASRC, int EPI, int KPAD>
__global__ __launch_bounds__(256, 3) void gemm4(
    const float* __restrict__ Af, int Kreal,
    const u16* __restrict__ Ab, const u16* __restrict__ Bw,
    const u16* __restrict__ addb, const float* __restrict__ bias,
    u16* __restrict__ outb0, float* __restrict__ outf) {
  const int tid = threadIdx.x;
  const int lane = tid & 63;
  const int wn = (tid >> 6) * 64;
  const int m0 = blockIdx.x * 32;
  const int lm = lane & 15, lg = lane >> 4;
  const int koff = lg * 8;

  f32x4 acc[2][4];
#pragma unroll
  for (int i = 0; i < 2; ++i)
#pragma unroll
    for (int j = 0; j < 4; ++j) acc[i][j] = (f32x4)(0.f);

#pragma unroll
  for (int kk = 0; kk < KPAD / 32; ++kk) {
    const int k0 = kk * 32 + koff;
    bf16x8 a[2];
#pragma unroll
    for (int im = 0; im < 2; ++im) {
      if constexpr (ASRC == 0) {
        const float* p = Af + (size_t)(m0 + im * 16 + lm) * Kreal + k0;
        union { bf16x8 v; u32 u[4]; } cv;
        if (k0 + 8 <= Kreal) {
#pragma unroll
          for (int e = 0; e < 4; ++e) cv.u[e] = pack2bf(p[2 * e], p[2 * e + 1]);
        } else {
#pragma unroll
          for (int e = 0; e < 4; ++e) {
            float x0 = (k0 + 2 * e < Kreal) ? p[2 * e] : 0.f;
            float x1 = (k0 + 2 * e + 1 < Kreal) ? p[2 * e + 1] : 0.f;
            cv.u[e] = pack2bf(x0, x1);
          }
        }
        a[im] = cv.v;
      } else {
        a[im] = *reinterpret_cast<const bf16x8*>(
            Ab + (size_t)(m0 + im * 16 + lm) * KPAD + k0);
      }
    }
#pragma unroll
    for (int jw = 0; jw < 4; ++jw) {
      bf16x8 b = *reinterpret_cast<const bf16x8*>(
          Bw + (size_t)(wn + jw * 16 + lm) * KPAD + k0);
      acc[0][jw] = __builtin_amdgcn_mfma_f32_16x16x32_bf16(b, a[0], acc[0][jw], 0, 0, 0);
      acc[1][jw] = __builtin_amdgcn_mfma_f32_16x16x32_bf16(b, a[1], acc[1][jw], 0, 0, 0);
    }
  }

#pragma unroll
  for (int im = 0; im < 2; ++im) {
#pragma unroll
    for (int jw = 0; jw < 4; ++jw) {
      const int r = m0 + im * 16 + lm;
      const int c0 = wn + jw * 16 + lg * 4;
      const size_t idx = (size_t)r * 256 + c0;
      f32x4 v = acc[im][jw];
      if constexpr (EPI == 0) {
        uint2 o; o.x = pack2bf(v[0], v[1]); o.y = pack2bf(v[2], v[3]);
        *reinterpret_cast<uint2*>(outb0 + idx) = o;
      } else if constexpr (EPI == 1) {
        const float4 bb = *reinterpret_cast<const float4*>(bias + c0);
        v[0] += bb.x; v[1] += bb.y; v[2] += bb.z; v[3] += bb.w;
        uint2 o; o.x = pack2bf(v[0], v[1]); o.y = pack2bf(v[2], v[3]);
        *reinterpret_cast<uint2*>(outb0 + idx) = o;
        float4 rl;
        rl.x = v[0] > 0.f ? v[0] : 0.f; rl.y = v[1] > 0.f ? v[1] : 0.f;
        rl.z = v[2] > 0.f ? v[2] : 0.f; rl.w = v[3] > 0.f ? v[3] : 0.f;
        *reinterpret_cast<float4*>(outf + idx) = rl;
      } else if constexpr (EPI == 2) {
        const uint2 ab = *reinterpret_cast<const uint2*>(addb + idx);
        v[0] += bflo(ab.x); v[1] += bfhi(ab.x);
        v[2] += bflo(ab.y); v[3] += bfhi(ab.y);
        uint2 o; o.x = pack2bf(v[0], v[1]); o.y = pack2bf(v[2], v[3]);
        *reinterpret_cast<uint2*>(outb0 + idx) = o;
      } else {
        const uint2 ab = *reinterpret_cast<const uint2*>(addb + idx);
        v[0] += bflo(ab.x); v[1] += bfhi(ab.x);
        v[2] += bflo(ab.y); v[3] += bfhi(ab.y);
        float4 rl;
        rl.x = v[0] > 0.f ? v[0] : 0.f; rl.y = v[1] > 0.f ? v[1] : 0.f;
        rl.z = v[2] > 0.f ? v[2] : 0.f; rl.w = v[3] > 0.f ? v[3] : 0.f;
        *reinterpret_cast<float4*>(outf + idx) = rl;
      }
    }
  }
}

// amsg[a][:] = sum_j relu(S[a2b[a][j]][:])  (bf16 pre-activation in, bf16 out)
__global__ __launch_bounds__(256) void gather_sum(const u16* __restrict__ S,
                                                  const int* __restrict__ a2b,
                                                  u16* __restrict__ amsg,
                                                  int n_atoms) {
  int wave = threadIdx.x >> 6, lane = threadIdx.x & 63;
  int atom = blockIdx.x * 4 + wave;
  if (atom >= n_atoms) return;
  float s0 = 0.f, s1 = 0.f, s2 = 0.f, s3 = 0.f;
  int base = atom * 6;
#pragma unroll
  for (int j = 0; j < 6; ++j) {
    int b = a2b[base + j];
    ushort4 v = *reinterpret_cast<const ushort4*>(S + (size_t)b * 256 + lane * 4);
    float x;
    x = bf2f(v.x); s0 += x > 0.f ? x : 0.f;
    x = bf2f(v.y); s1 += x > 0.f ? x : 0.f;
    x = bf2f(v.z); s2 += x > 0.f ? x : 0.f;
    x = bf2f(v.w); s3 += x > 0.f ? x : 0.f;
  }
  uint2 o;
  o.x = pack2bf(s0, s1);
  o.y = pack2bf(s2, s3);
  *reinterpret_cast<uint2*>(amsg + (size_t)atom * 256 + lane * 4) = o;
}

// pm[r][:] = amsg[b2a[r]][:] - relu(S[b2revb[r]][:])   (bf16)
__global__ __launch_bounds__(256) void bond_sub(const u16* __restrict__ amsg,
                                                const u16* __restrict__ S,
                                                const int* __restrict__ b2a,
                                                const int* __restrict__ b2revb,
                                                u16* __restrict__ pm, int nb) {
  int wave = threadIdx.x >> 6, lane = threadIdx.x & 63;
  int b = blockIdx.x * 4 + wave;
  if (b >= nb) return;
  int r1 = b2a[b], r2 = b2revb[b];
  uint2 va = *reinterpret_cast<const uint2*>(amsg + (size_t)r1 * 256 + lane * 4);
  uint2 vb = *reinterpret_cast<const uint2*>(S + (size_t)r2 * 256 + lane * 4);
  float a0 = bflo(va.x), a1 = bfhi(va.x), a2 = bflo(va.y), a3 = bfhi(va.y);
  float b0 = bflo(vb.x), b1 = bfhi(vb.x), b2 = bflo(vb.y), b3 = bfhi(vb.y);
  b0 = b0 > 0.f ? b0 : 0.f; b1 = b1 > 0.f ? b1 : 0.f;
  b2 = b2 > 0.f ? b2 : 0.f; b3 = b3 > 0.f ? b3 : 0.f;
  uint2 o;
  o.x = pack2bf(a0 - b0, a1 - b1);
  o.y = pack2bf(a2 - b2, a3 - b3);
  *reinterpret_cast<uint2*>(pm + (size_t)b * 256 + lane * 4) = o;
}

__global__ __launch_bounds__(256) void mol_mean(const float* __restrict__ dfin,
                                                float* __restrict__ out) {
  int mol = blockIdx.x, c = threadIdx.x;
  const float* p = dfin + (size_t)mol * (42 * 256) + c;
  float s = 0.f;
#pragma unroll
  for (int a = 0; a < 42; ++a) s += p[a * 256];
  out[(size_t)mol * 256 + c] = s * (1.0f / 42.0f);
}

extern "C" void kernel_launch(void* const* d_in, const int* in_sizes, int n_in,
                              void* d_out, int out_size, void* d_ws,
                              size_t ws_size, hipStream_t stream) {
  const float* f_atoms = (const float*)d_in[0];
  const float* f_bonds = (const float*)d_in[1];
  const float* W_i = (const float*)d_in[2];
  const float* W_h = (const float*)d_in[3];
  const float* W_o = (const float*)d_in[4];
  const float* b_o = (const float*)d_in[5];
  const int* a2b = (const int*)d_in[6];
  const int* b2a = (const int*)d_in[7];
  const int* b2revb = (const int*)d_in[8];

  const int NA = 168000, NB = 360000, H = 256;
  const size_t SZ_BH = (size_t)NB * H * 2;
  const size_t SZ_AH = (size_t)NA * H * 2;

  char* ws = (char*)d_ws;
  u16* inp_b = (u16*)ws;  ws += SZ_BH;   // S_0 (pre-act bond state, = inp)
  u16* P0    = (u16*)ws;  ws += SZ_BH;   // bond_sub output (W_h GEMM input)
  u16* P1    = (u16*)ws;  ws += SZ_BH;   // W_h GEMM output (S_1 / S_2)
  u16* amsg  = (u16*)ws;  ws += SZ_AH;
  u16* base_b = (u16*)ws; ws += SZ_AH;
  u16* Wi_b  = (u16*)ws;  ws += 256 * 160 * 2;
  u16* Wh_b  = (u16*)ws;  ws += 256 * 256 * 2;
  u16* Wo1_b = (u16*)ws;  ws += 256 * 160 * 2;
  u16* Wo2_b = (u16*)ws;  ws += 256 * 256 * 2;

  float* out = (float*)d_out;
  float* d0 = out;
  float* d1 = d0 + (size_t)NA * H;
  float* d2 = d1 + (size_t)NA * H;
  float* dfin = d2 + (size_t)NA * H;
  float* mol = dfin + (size_t)NA * H;

  dim3 blk(256);
  cvt_w<<<dim3((256 * 160 + 255) / 256), blk, 0, stream>>>(W_i, Wi_b, 256, 147, 160, 147, 0);
  cvt_w<<<dim3((256 * 256 + 255) / 256), blk, 0, stream>>>(W_h, Wh_b, 256, 256, 256, 256, 0);
  cvt_w<<<dim3((256 * 160 + 255) / 256), blk, 0, stream>>>(W_o, Wo1_b, 256, 133, 160, 389, 0);
  cvt_w<<<dim3((256 * 256 + 255) / 256), blk, 0, stream>>>(W_o, Wo2_b, 256, 256, 256, 389, 133);

  // inp = f_bonds @ W_i^T  (pre-activation; relu fused into consumers)
  gemm4<0, 0, 160><<<dim3(NB / 32), blk, 0, stream>>>(
      f_bonds, 147, nullptr, Wi_b, nullptr, nullptr, inp_b, nullptr);
  // base = f_atoms @ W_o1^T + b_o (pre-relu, bf16) ; d0 = relu(base) f32
  gemm4<0, 1, 160><<<dim3(NA / 32), blk, 0, stream>>>(
      f_atoms, 133, nullptr, Wo1_b, nullptr, b_o, base_b, d0);

  u16* S = inp_b;
  float* douts[3] = {d1, d2, dfin};
  for (int d = 0; d < 3; ++d) {
    gather_sum<<<dim3(NA / 4), blk, 0, stream>>>(S, a2b, amsg, NA);
    // d_{d+1} = relu(base + amsg @ W_o2^T)
    gemm4<1, 3, 256><<<dim3(NA / 32), blk, 0, stream>>>(
        nullptr, 0, amsg, Wo2_b, base_b, nullptr, nullptr, douts[d]);
    if (d < 2) {
      // P0 = amsg[b2a] - relu(S[b2revb])   (S fully consumed this iter)
      bond_sub<<<dim3(NB / 4), blk, 0, stream>>>(amsg, S, b2a, b2revb, P0, NB);
      // P1 = inp + P0 @ W_h^T   (pre-activation; P1's old content is dead)
      gemm4<1, 2, 256><<<dim3(NB / 32), blk, 0, stream>>>(
          nullptr, 0, P0, Wh_b, inp_b, nullptr, P1, nullptr);
      S = P1;
    }
  }
  mol_mean<<<dim3(4000), blk, 0, stream>>>(dfin, mol);
}

// Round 6
// 1553.159 us; speedup vs baseline: 1.5985x; 1.3296x over previous
//
#include <hip/hip_runtime.h>

typedef unsigned short u16;
typedef unsigned int u32;
typedef __bf16 bf16x8 __attribute__((ext_vector_type(8)));
typedef float f32x4 __attribute__((ext_vector_type(4)));

__device__ __forceinline__ float bf2f(u16 h) {
  union { u32 u; float f; } c; c.u = ((u32)h) << 16; return c.f;
}
__device__ __forceinline__ float bflo(u32 u) {
  union { u32 u; float f; } c; c.u = u << 16; return c.f;
}
__device__ __forceinline__ float bfhi(u32 u) {
  union { u32 u; float f; } c; c.u = u & 0xffff0000u; return c.f;
}
// compiler emits packed v_cvt_pk_bf16_f32 for __bf16 casts (RNE)
__device__ __forceinline__ u32 pack2bf(float a, float b) {
  union { __bf16 h[2]; u32 u; } c; c.h[0] = (__bf16)a; c.h[1] = (__bf16)b;
  return c.u;
}
__device__ __forceinline__ u16 f2bf(float f) {
  union { __bf16 h; u16 u; } c; c.h = (__bf16)f; return c.u;
}
__device__ __forceinline__ float relu(float x) { return x > 0.f ? x : 0.f; }

// Convert a weight slice W[n, col0 + k] (f32, row stride src_stride) into
// bf16 [N][Kd] zero-padded along K.
__global__ __launch_bounds__(256) void cvt_w(const float* __restrict__ src,
                                             u16* __restrict__ dst, int N,
                                             int Ks, int Kd, int src_stride,
                                             int col0) {
  int i = blockIdx.x * 256 + threadIdx.x;
  if (i >= N * Kd) return;
  int n = i / Kd, k = i % Kd;
  float v = (k < Ks) ? src[(size_t)n * src_stride + col0 + k] : 0.f;
  dst[i] = f2bf(v);
}

// GEMM: C[M,256] = A[M,K] * W[256,K]^T.  BM=64, BN=256; 4 waves, each
// 64 rows x 64-col band.  A staged COALESCED into LDS once (1 barrier);
// B-fragments read from global (weights L2-resident, broadcast).
// Swapped-operand MFMA: acc = mfma(w_frag, a_frag) -> lane holds 4
// consecutive output columns (c0 = wn + jw*16 + (lane>>4)*4) at row
// m0 + im*16 + (lane&15).  Stores: bf16 = 8B uint2, f32 = 16B float4.
// Output must not alias any input buffer (cross-wave WAR, round-4 lesson).
// ASRC: 0 = A from f32 global [M][Kreal] (k<Kreal guard, converted)
//       1 = A from bf16 global [M][KPAD]
//       2 = A row r = bf16( Ab[idx1[r]] - relu(Ab2[idx2[r]]) )  [KPAD=256]
// EPI:  0 = bf16 acc -> outb0
//       1 = v=acc+bias[c]; bf16 v -> outb0; relu(v) f32 -> outf
//       2 = v=acc+bf2f(addb[idx]); bf16 v -> outb0   (pre-activation store)
//       3 = v=acc+bf2f(addb[idx]); relu(v) f32 -> outf
template <int ASRC, int EPI, int KPAD>
__global__ __launch_bounds__(256, 3) void gemm5(
    const float* __restrict__ Af, int Kreal,
    const u16* __restrict__ Ab, const u16* __restrict__ Ab2,
    const int* __restrict__ idx1, const int* __restrict__ idx2,
    const u16* __restrict__ Bw,
    const u16* __restrict__ addb, const float* __restrict__ bias,
    u16* __restrict__ outb0, float* __restrict__ outf) {
  constexpr int LDK = KPAD + 8;  // row stride 336/528B: 2-way bank alias (free)
  __shared__ u16 As[64 * LDK];

  const int tid = threadIdx.x;
  const int lane = tid & 63;
  const int wn = (tid >> 6) * 64;
  const int m0 = blockIdx.x * 64;
  const int lm = lane & 15, lg = lane >> 4;
  const int koff = lg * 8;

  // ---- coalesced staging of A[64][KPAD] ----
  if constexpr (ASRC == 0) {
    // consecutive lanes -> consecutive k pairs (8B apart): coalesced dwords
#pragma unroll
    for (int p = 0; p < 64 * KPAD / 512; ++p) {
      int e = (p * 256 + tid) * 2;
      int row = e / KPAD, k = e % KPAD;
      const float* src = Af + (size_t)(m0 + row) * Kreal + k;
      float x0 = (k < Kreal) ? src[0] : 0.f;
      float x1 = (k + 1 < Kreal) ? src[1] : 0.f;
      *reinterpret_cast<u32*>(&As[row * LDK + k]) = pack2bf(x0, x1);
    }
  } else if constexpr (ASRC == 1) {
    // consecutive lanes -> consecutive 16B chunks: perfectly coalesced
#pragma unroll
    for (int p = 0; p < 64 * KPAD / 8 / 256; ++p) {
      int ch = p * 256 + tid;
      int row = ch / (KPAD / 8), c8 = ch % (KPAD / 8);
      uint4 v = *reinterpret_cast<const uint4*>(Ab + (size_t)(m0 + row) * KPAD + c8 * 8);
      *reinterpret_cast<uint4*>(&As[row * LDK + c8 * 8]) = v;
    }
  } else {
    // fused gather-subtract: 4 threads per row, 128B segment each per source
    static_assert(KPAD == 256, "ASRC2 assumes KPAD=256");
    const int row = tid >> 2, seg = tid & 3;
    const int gr = m0 + row;
    const int r1 = idx1[gr], r2 = idx2[gr];
    const u16* pa = Ab + (size_t)r1 * KPAD + seg * 64;
    const u16* pb = Ab2 + (size_t)r2 * KPAD + seg * 64;
    uint4 va[8], vb[8];
#pragma unroll
    for (int i = 0; i < 8; ++i) va[i] = *reinterpret_cast<const uint4*>(pa + i * 8);
#pragma unroll
    for (int i = 0; i < 8; ++i) vb[i] = *reinterpret_cast<const uint4*>(pb + i * 8);
    u16* dst = &As[row * LDK + seg * 64];
#pragma unroll
    for (int i = 0; i < 8; ++i) {
      uint4 o;
      o.x = pack2bf(bflo(va[i].x) - relu(bflo(vb[i].x)),
                    bfhi(va[i].x) - relu(bfhi(vb[i].x)));
      o.y = pack2bf(bflo(va[i].y) - relu(bflo(vb[i].y)),
                    bfhi(va[i].y) - relu(bfhi(vb[i].y)));
      o.z = pack2bf(bflo(va[i].z) - relu(bflo(vb[i].z)),
                    bfhi(va[i].z) - relu(bfhi(vb[i].z)));
      o.w = pack2bf(bflo(va[i].w) - relu(bflo(vb[i].w)),
                    bfhi(va[i].w) - relu(bfhi(vb[i].w)));
      *reinterpret_cast<uint4*>(dst + i * 8) = o;
    }
  }
  __syncthreads();

  f32x4 acc[4][4];
#pragma unroll
  for (int i = 0; i < 4; ++i)
#pragma unroll
    for (int j = 0; j < 4; ++j) acc[i][j] = (f32x4)(0.f);

#pragma unroll
  for (int kk = 0; kk < KPAD / 32; ++kk) {
    const int k0 = kk * 32 + koff;
    bf16x8 a[4];
#pragma unroll
    for (int im = 0; im < 4; ++im)
      a[im] = *reinterpret_cast<const bf16x8*>(&As[(im * 16 + lm) * LDK + k0]);
#pragma unroll
    for (int jw = 0; jw < 4; ++jw) {
      bf16x8 b = *reinterpret_cast<const bf16x8*>(
          Bw + (size_t)(wn + jw * 16 + lm) * KPAD + k0);
#pragma unroll
      for (int im = 0; im < 4; ++im)
        acc[im][jw] = __builtin_amdgcn_mfma_f32_16x16x32_bf16(b, a[im], acc[im][jw], 0, 0, 0);
    }
  }

#pragma unroll
  for (int im = 0; im < 4; ++im) {
#pragma unroll
    for (int jw = 0; jw < 4; ++jw) {
      const int r = m0 + im * 16 + lm;
      const int c0 = wn + jw * 16 + lg * 4;
      const size_t idx = (size_t)r * 256 + c0;
      f32x4 v = acc[im][jw];
      if constexpr (EPI == 0) {
        uint2 o; o.x = pack2bf(v[0], v[1]); o.y = pack2bf(v[2], v[3]);
        *reinterpret_cast<uint2*>(outb0 + idx) = o;
      } else if constexpr (EPI == 1) {
        const float4 bb = *reinterpret_cast<const float4*>(bias + c0);
        v[0] += bb.x; v[1] += bb.y; v[2] += bb.z; v[3] += bb.w;
        uint2 o; o.x = pack2bf(v[0], v[1]); o.y = pack2bf(v[2], v[3]);
        *reinterpret_cast<uint2*>(outb0 + idx) = o;
        float4 rl = {relu(v[0]), relu(v[1]), relu(v[2]), relu(v[3])};
        *reinterpret_cast<float4*>(outf + idx) = rl;
      } else if constexpr (EPI == 2) {
        const uint2 ab = *reinterpret_cast<const uint2*>(addb + idx);
        v[0] += bflo(ab.x); v[1] += bfhi(ab.x);
        v[2] += bflo(ab.y); v[3] += bfhi(ab.y);
        uint2 o; o.x = pack2bf(v[0], v[1]); o.y = pack2bf(v[2], v[3]);
        *reinterpret_cast<uint2*>(outb0 + idx) = o;
      } else {
        const uint2 ab = *reinterpret_cast<const uint2*>(addb + idx);
        v[0] += bflo(ab.x); v[1] += bfhi(ab.x);
        v[2] += bflo(ab.y); v[3] += bfhi(ab.y);
        float4 rl = {relu(v[0]), relu(v[1]), relu(v[2]), relu(v[3])};
        *reinterpret_cast<float4*>(outf + idx) = rl;
      }
    }
  }
}

// amsg[a][:] = sum_j relu(S[a2b[a][j]][:])  (bf16 pre-activation in, bf16 out)
__global__ __launch_bounds__(256) void gather_sum(const u16* __restrict__ S,
                                                  const int* __restrict__ a2b,
                                                  u16* __restrict__ amsg,
                                                  int n_atoms) {
  int wave = threadIdx.x >> 6, lane = threadIdx.x & 63;
  int atom = blockIdx.x * 4 + wave;
  if (atom >= n_atoms) return;
  float s0 = 0.f, s1 = 0.f, s2 = 0.f, s3 = 0.f;
  int base = atom * 6;
#pragma unroll
  for (int j = 0; j < 6; ++j) {
    int b = a2b[base + j];
    ushort4 v = *reinterpret_cast<const ushort4*>(S + (size_t)b * 256 + lane * 4);
    s0 += relu(bf2f(v.x));
    s1 += relu(bf2f(v.y));
    s2 += relu(bf2f(v.z));
    s3 += relu(bf2f(v.w));
  }
  uint2 o;
  o.x = pack2bf(s0, s1);
  o.y = pack2bf(s2, s3);
  *reinterpret_cast<uint2*>(amsg + (size_t)atom * 256 + lane * 4) = o;
}

__global__ __launch_bounds__(256) void mol_mean(const float* __restrict__ dfin,
                                                float* __restrict__ out) {
  int mol = blockIdx.x, c = threadIdx.x;
  const float* p = dfin + (size_t)mol * (42 * 256) + c;
  float s = 0.f;
#pragma unroll
  for (int a = 0; a < 42; ++a) s += p[a * 256];
  out[(size_t)mol * 256 + c] = s * (1.0f / 42.0f);
}

extern "C" void kernel_launch(void* const* d_in, const int* in_sizes, int n_in,
                              void* d_out, int out_size, void* d_ws,
                              size_t ws_size, hipStream_t stream) {
  const float* f_atoms = (const float*)d_in[0];
  const float* f_bonds = (const float*)d_in[1];
  const float* W_i = (const float*)d_in[2];
  const float* W_h = (const float*)d_in[3];
  const float* W_o = (const float*)d_in[4];
  const float* b_o = (const float*)d_in[5];
  const int* a2b = (const int*)d_in[6];
  const int* b2a = (const int*)d_in[7];
  const int* b2revb = (const int*)d_in[8];

  const int NA = 168000, NB = 360000, H = 256;
  const size_t SZ_BH = (size_t)NB * H * 2;
  const size_t SZ_AH = (size_t)NA * H * 2;

  char* ws = (char*)d_ws;
  u16* inp_b = (u16*)ws;  ws += SZ_BH;   // S_0 (pre-act bond state = inp)
  u16* P0    = (u16*)ws;  ws += SZ_BH;   // S_1
  u16* P1    = (u16*)ws;  ws += SZ_BH;   // S_2
  u16* amsg  = (u16*)ws;  ws += SZ_AH;
  u16* base_b = (u16*)ws; ws += SZ_AH;
  u16* Wi_b  = (u16*)ws;  ws += 256 * 160 * 2;
  u16* Wh_b  = (u16*)ws;  ws += 256 * 256 * 2;
  u16* Wo1_b = (u16*)ws;  ws += 256 * 160 * 2;
  u16* Wo2_b = (u16*)ws;  ws += 256 * 256 * 2;

  float* out = (float*)d_out;
  float* d0 = out;
  float* d1 = d0 + (size_t)NA * H;
  float* d2 = d1 + (size_t)NA * H;
  float* dfin = d2 + (size_t)NA * H;
  float* mol = dfin + (size_t)NA * H;

  dim3 blk(256);
  cvt_w<<<dim3((256 * 160 + 255) / 256), blk, 0, stream>>>(W_i, Wi_b, 256, 147, 160, 147, 0);
  cvt_w<<<dim3((256 * 256 + 255) / 256), blk, 0, stream>>>(W_h, Wh_b, 256, 256, 256, 256, 0);
  cvt_w<<<dim3((256 * 160 + 255) / 256), blk, 0, stream>>>(W_o, Wo1_b, 256, 133, 160, 389, 0);
  cvt_w<<<dim3((256 * 256 + 255) / 256), blk, 0, stream>>>(W_o, Wo2_b, 256, 256, 256, 389, 133);

  // inp = f_bonds @ W_i^T  (pre-activation; relu fused into consumers)
  gemm5<0, 0, 160><<<dim3(NB / 64), blk, 0, stream>>>(
      f_bonds, 147, nullptr, nullptr, nullptr, nullptr, Wi_b,
      nullptr, nullptr, inp_b, nullptr);
  // base = f_atoms @ W_o1^T + b_o (pre-relu, bf16) ; d0 = relu(base) f32
  gemm5<0, 1, 160><<<dim3(NA / 64), blk, 0, stream>>>(
      f_atoms, 133, nullptr, nullptr, nullptr, nullptr, Wo1_b,
      nullptr, b_o, base_b, d0);

  u16* S = inp_b;
  u16* pms[2] = {P0, P1};
  float* douts[3] = {d1, d2, dfin};
  for (int d = 0; d < 3; ++d) {
    gather_sum<<<dim3(NA / 4), blk, 0, stream>>>(S, a2b, amsg, NA);
    // d_{d+1} = relu(base + amsg @ W_o2^T)
    gemm5<1, 3, 256><<<dim3(NA / 64), blk, 0, stream>>>(
        nullptr, 0, amsg, nullptr, nullptr, nullptr, Wo2_b,
        base_b, nullptr, nullptr, douts[d]);
    if (d < 2) {
      // S' = inp + (amsg[b2a] - relu(S[b2revb])) @ W_h^T  (gather fused)
      gemm5<2, 2, 256><<<dim3(NB / 64), blk, 0, stream>>>(
          nullptr, 0, amsg, S, b2a, b2revb, Wh_b,
          inp_b, nullptr, pms[d], nullptr);
      S = pms[d];
    }
  }
  mol_mean<<<dim3(4000), blk, 0, stream>>>(dfin, mol);
}

// Round 7
// 1474.356 us; speedup vs baseline: 1.6840x; 1.0534x over previous
//
#include <hip/hip_runtime.h>

typedef unsigned short u16;
typedef unsigned int u32;
typedef __bf16 bf16x8 __attribute__((ext_vector_type(8)));
typedef float f32x4 __attribute__((ext_vector_type(4)));

__device__ __forceinline__ float bf2f(u16 h) {
  union { u32 u; float f; } c; c.u = ((u32)h) << 16; return c.f;
}
__device__ __forceinline__ float bflo(u32 u) {
  union { u32 u; float f; } c; c.u = u << 16; return c.f;
}
__device__ __forceinline__ float bfhi(u32 u) {
  union { u32 u; float f; } c; c.u = u & 0xffff0000u; return c.f;
}
// compiler emits packed v_cvt_pk_bf16_f32 for __bf16 casts (RNE)
__device__ __forceinline__ u32 pack2bf(float a, float b) {
  union { __bf16 h[2]; u32 u; } c; c.h[0] = (__bf16)a; c.h[1] = (__bf16)b;
  return c.u;
}
__device__ __forceinline__ u16 f2bf(float f) {
  union { __bf16 h; u16 u; } c; c.h = (__bf16)f; return c.u;
}
__device__ __forceinline__ float relu(float x) { return x > 0.f ? x : 0.f; }

// Convert a weight slice W[n, col0 + k] (f32, row stride src_stride) into
// bf16 [N][Kd] zero-padded along K.
__global__ __launch_bounds__(256) void cvt_w(const float* __restrict__ src,
                                             u16* __restrict__ dst, int N,
                                             int Ks, int Kd, int src_stride,
                                             int col0) {
  int i = blockIdx.x * 256 + threadIdx.x;
  if (i >= N * Kd) return;
  int n = i / Kd, k = i % Kd;
  float v = (k < Ks) ? src[(size_t)n * src_stride + col0 + k] : 0.f;
  dst[i] = f2bf(v);
}

// GEMM: C[M,256] = A[M,K] * W[256,K]^T.  BM=64, BN=256; 4 waves, each
// 64 rows x 64-col band.  A staged COALESCED into LDS once (1 barrier);
// B-fragments read from global (weights L2-resident, broadcast).
// Swapped-operand MFMA: acc = mfma(w_frag, a_frag) -> lane holds 4
// consecutive output columns (c0 = wn + jw*16 + (lane>>4)*4) at row
// m0 + im*16 + (lane&15).  Stores: bf16 = 8B uint2, f32 = 16B float4.
// Output must not alias any input buffer (cross-wave WAR, round-4 lesson).
// ASRC: 0 = A from f32 global [M][Kreal] (k<Kreal guard, converted)
//       1 = A from bf16 global [M][KPAD]
//       2 = A row r = bf16( Ab[idx1[r]] - relu(Ab2[idx2[r]]) )  [KPAD=256]
//       3 = A row r = bf16( sum_{j<6} relu(Ab[idx1[r*6+j]]) )   [KPAD=256]
//           (fused gather_sum; if WAMSG, also store staged rows to amsg_out)
// EPI:  0 = bf16 acc -> outb0
//       1 = v=acc+bias[c]; bf16 v -> outb0; relu(v) f32 -> outf
//       2 = v=acc+bf2f(addb[idx]); bf16 v -> outb0   (pre-activation store)
//       3 = v=acc+bf2f(addb[idx]); relu(v) f32 -> outf
template <int ASRC, int EPI, int KPAD, int WAMSG, int MINW>
__global__ __launch_bounds__(256, MINW) void gemm6(
    const float* __restrict__ Af, int Kreal,
    const u16* __restrict__ Ab, const u16* __restrict__ Ab2,
    const int* __restrict__ idx1, const int* __restrict__ idx2,
    const u16* __restrict__ Bw,
    const u16* __restrict__ addb, const float* __restrict__ bias,
    u16* __restrict__ outb0, float* __restrict__ outf,
    u16* __restrict__ amsg_out) {
  constexpr int LDK = KPAD + 8;  // row stride 336/528B: 2-way bank alias (free)
  __shared__ u16 As[64 * LDK];

  const int tid = threadIdx.x;
  const int lane = tid & 63;
  const int wn = (tid >> 6) * 64;
  const int m0 = blockIdx.x * 64;
  const int lm = lane & 15, lg = lane >> 4;
  const int koff = lg * 8;

  // ---- coalesced staging of A[64][KPAD] ----
  if constexpr (ASRC == 0) {
    // consecutive lanes -> consecutive k pairs (8B apart): coalesced dwords
#pragma unroll
    for (int p = 0; p < 64 * KPAD / 512; ++p) {
      int e = (p * 256 + tid) * 2;
      int row = e / KPAD, k = e % KPAD;
      const float* src = Af + (size_t)(m0 + row) * Kreal + k;
      float x0 = (k < Kreal) ? src[0] : 0.f;
      float x1 = (k + 1 < Kreal) ? src[1] : 0.f;
      *reinterpret_cast<u32*>(&As[row * LDK + k]) = pack2bf(x0, x1);
    }
  } else if constexpr (ASRC == 1) {
    // consecutive lanes -> consecutive 16B chunks: perfectly coalesced
#pragma unroll
    for (int p = 0; p < 64 * KPAD / 8 / 256; ++p) {
      int ch = p * 256 + tid;
      int row = ch / (KPAD / 8), c8 = ch % (KPAD / 8);
      uint4 v = *reinterpret_cast<const uint4*>(Ab + (size_t)(m0 + row) * KPAD + c8 * 8);
      *reinterpret_cast<uint4*>(&As[row * LDK + c8 * 8]) = v;
    }
  } else if constexpr (ASRC == 2) {
    // fused gather-subtract: 4 threads per row, 128B segment each per source
    static_assert(KPAD == 256, "ASRC2 assumes KPAD=256");
    const int row = tid >> 2, seg = tid & 3;
    const int gr = m0 + row;
    const int r1 = idx1[gr], r2 = idx2[gr];
    const u16* pa = Ab + (size_t)r1 * KPAD + seg * 64;
    const u16* pb = Ab2 + (size_t)r2 * KPAD + seg * 64;
    uint4 va[8], vb[8];
#pragma unroll
    for (int i = 0; i < 8; ++i) va[i] = *reinterpret_cast<const uint4*>(pa + i * 8);
#pragma unroll
    for (int i = 0; i < 8; ++i) vb[i] = *reinterpret_cast<const uint4*>(pb + i * 8);
    u16* dst = &As[row * LDK + seg * 64];
#pragma unroll
    for (int i = 0; i < 8; ++i) {
      uint4 o;
      o.x = pack2bf(bflo(va[i].x) - relu(bflo(vb[i].x)),
                    bfhi(va[i].x) - relu(bfhi(vb[i].x)));
      o.y = pack2bf(bflo(va[i].y) - relu(bflo(vb[i].y)),
                    bfhi(va[i].y) - relu(bfhi(vb[i].y)));
      o.z = pack2bf(bflo(va[i].z) - relu(bflo(vb[i].z)),
                    bfhi(va[i].z) - relu(bfhi(vb[i].z)));
      o.w = pack2bf(bflo(va[i].w) - relu(bflo(vb[i].w)),
                    bfhi(va[i].w) - relu(bfhi(vb[i].w)));
      *reinterpret_cast<uint4*>(dst + i * 8) = o;
    }
  } else {
    // fused gather_sum: 8 threads per row (64B seg), 2 passes of 32 rows.
    static_assert(KPAD == 256, "ASRC3 assumes KPAD=256");
#pragma unroll
    for (int pass = 0; pass < 2; ++pass) {
      const int row = pass * 32 + (tid >> 3);
      const int seg = tid & 7;  // 32 u16 = 64B per seg
      const int gr = m0 + row;
      const int* nb = idx1 + gr * 6;
      float s[32];
#pragma unroll
      for (int e = 0; e < 32; ++e) s[e] = 0.f;
      for (int j = 0; j < 6; ++j) {
        const u16* p = Ab + (size_t)nb[j] * 256 + seg * 32;
#pragma unroll
        for (int c = 0; c < 4; ++c) {
          uint4 v = *reinterpret_cast<const uint4*>(p + c * 8);
          s[c * 8 + 0] += relu(bflo(v.x));
          s[c * 8 + 1] += relu(bfhi(v.x));
          s[c * 8 + 2] += relu(bflo(v.y));
          s[c * 8 + 3] += relu(bfhi(v.y));
          s[c * 8 + 4] += relu(bflo(v.z));
          s[c * 8 + 5] += relu(bfhi(v.z));
          s[c * 8 + 6] += relu(bflo(v.w));
          s[c * 8 + 7] += relu(bfhi(v.w));
        }
      }
      u16* dst = &As[row * LDK + seg * 32];
#pragma unroll
      for (int c = 0; c < 4; ++c) {
        uint4 o;
        o.x = pack2bf(s[c * 8 + 0], s[c * 8 + 1]);
        o.y = pack2bf(s[c * 8 + 2], s[c * 8 + 3]);
        o.z = pack2bf(s[c * 8 + 4], s[c * 8 + 5]);
        o.w = pack2bf(s[c * 8 + 6], s[c * 8 + 7]);
        *reinterpret_cast<uint4*>(dst + c * 8) = o;
        if constexpr (WAMSG)
          *reinterpret_cast<uint4*>(amsg_out + (size_t)gr * 256 + seg * 32 + c * 8) = o;
      }
    }
  }
  __syncthreads();

  f32x4 acc[4][4];
#pragma unroll
  for (int i = 0; i < 4; ++i)
#pragma unroll
    for (int j = 0; j < 4; ++j) acc[i][j] = (f32x4)(0.f);

#pragma unroll
  for (int kk = 0; kk < KPAD / 32; ++kk) {
    const int k0 = kk * 32 + koff;
    bf16x8 a[4];
#pragma unroll
    for (int im = 0; im < 4; ++im)
      a[im] = *reinterpret_cast<const bf16x8*>(&As[(im * 16 + lm) * LDK + k0]);
#pragma unroll
    for (int jw = 0; jw < 4; ++jw) {
      bf16x8 b = *reinterpret_cast<const bf16x8*>(
          Bw + (size_t)(wn + jw * 16 + lm) * KPAD + k0);
#pragma unroll
      for (int im = 0; im < 4; ++im)
        acc[im][jw] = __builtin_amdgcn_mfma_f32_16x16x32_bf16(b, a[im], acc[im][jw], 0, 0, 0);
    }
  }

#pragma unroll
  for (int im = 0; im < 4; ++im) {
#pragma unroll
    for (int jw = 0; jw < 4; ++jw) {
      const int r = m0 + im * 16 + lm;
      const int c0 = wn + jw * 16 + lg * 4;
      const size_t idx = (size_t)r * 256 + c0;
      f32x4 v = acc[im][jw];
      if constexpr (EPI == 0) {
        uint2 o; o.x = pack2bf(v[0], v[1]); o.y = pack2bf(v[2], v[3]);
        *reinterpret_cast<uint2*>(outb0 + idx) = o;
      } else if constexpr (EPI == 1) {
        const float4 bb = *reinterpret_cast<const float4*>(bias + c0);
        v[0] += bb.x; v[1] += bb.y; v[2] += bb.z; v[3] += bb.w;
        uint2 o; o.x = pack2bf(v[0], v[1]); o.y = pack2bf(v[2], v[3]);
        *reinterpret_cast<uint2*>(outb0 + idx) = o;
        float4 rl = {relu(v[0]), relu(v[1]), relu(v[2]), relu(v[3])};
        *reinterpret_cast<float4*>(outf + idx) = rl;
      } else if constexpr (EPI == 2) {
        const uint2 ab = *reinterpret_cast<const uint2*>(addb + idx);
        v[0] += bflo(ab.x); v[1] += bfhi(ab.x);
        v[2] += bflo(ab.y); v[3] += bfhi(ab.y);
        uint2 o; o.x = pack2bf(v[0], v[1]); o.y = pack2bf(v[2], v[3]);
        *reinterpret_cast<uint2*>(outb0 + idx) = o;
      } else {
        const uint2 ab = *reinterpret_cast<const uint2*>(addb + idx);
        v[0] += bflo(ab.x); v[1] += bfhi(ab.x);
        v[2] += bflo(ab.y); v[3] += bfhi(ab.y);
        float4 rl = {relu(v[0]), relu(v[1]), relu(v[2]), relu(v[3])};
        *reinterpret_cast<float4*>(outf + idx) = rl;
      }
    }
  }
}

__global__ __launch_bounds__(256) void mol_mean(const float* __restrict__ dfin,
                                                float* __restrict__ out) {
  int mol = blockIdx.x, c = threadIdx.x;
  const float* p = dfin + (size_t)mol * (42 * 256) + c;
  float s = 0.f;
#pragma unroll
  for (int a = 0; a < 42; ++a) s += p[a * 256];
  out[(size_t)mol * 256 + c] = s * (1.0f / 42.0f);
}

extern "C" void kernel_launch(void* const* d_in, const int* in_sizes, int n_in,
                              void* d_out, int out_size, void* d_ws,
                              size_t ws_size, hipStream_t stream) {
  const float* f_atoms = (const float*)d_in[0];
  const float* f_bonds = (const float*)d_in[1];
  const float* W_i = (const float*)d_in[2];
  const float* W_h = (const float*)d_in[3];
  const float* W_o = (const float*)d_in[4];
  const float* b_o = (const float*)d_in[5];
  const int* a2b = (const int*)d_in[6];
  const int* b2a = (const int*)d_in[7];
  const int* b2revb = (const int*)d_in[8];

  const int NA = 168000, NB = 360000, H = 256;
  const size_t SZ_BH = (size_t)NB * H * 2;
  const size_t SZ_AH = (size_t)NA * H * 2;

  char* ws = (char*)d_ws;
  u16* inp_b = (u16*)ws;  ws += SZ_BH;   // S_0 (pre-act bond state = inp)
  u16* P0    = (u16*)ws;  ws += SZ_BH;   // S_1
  u16* P1    = (u16*)ws;  ws += SZ_BH;   // S_2
  u16* amsg  = (u16*)ws;  ws += SZ_AH;
  u16* base_b = (u16*)ws; ws += SZ_AH;
  u16* Wi_b  = (u16*)ws;  ws += 256 * 160 * 2;
  u16* Wh_b  = (u16*)ws;  ws += 256 * 256 * 2;
  u16* Wo1_b = (u16*)ws;  ws += 256 * 160 * 2;
  u16* Wo2_b = (u16*)ws;  ws += 256 * 256 * 2;

  float* out = (float*)d_out;
  float* d0 = out;
  float* d1 = d0 + (size_t)NA * H;
  float* d2 = d1 + (size_t)NA * H;
  float* dfin = d2 + (size_t)NA * H;
  float* mol = dfin + (size_t)NA * H;

  dim3 blk(256);
  cvt_w<<<dim3((256 * 160 + 255) / 256), blk, 0, stream>>>(W_i, Wi_b, 256, 147, 160, 147, 0);
  cvt_w<<<dim3((256 * 256 + 255) / 256), blk, 0, stream>>>(W_h, Wh_b, 256, 256, 256, 256, 0);
  cvt_w<<<dim3((256 * 160 + 255) / 256), blk, 0, stream>>>(W_o, Wo1_b, 256, 133, 160, 389, 0);
  cvt_w<<<dim3((256 * 256 + 255) / 256), blk, 0, stream>>>(W_o, Wo2_b, 256, 256, 256, 389, 133);

  // inp = f_bonds @ W_i^T  (pre-activation; relu fused into consumers)
  gemm6<0, 0, 160, 0, 4><<<dim3(NB / 64), blk, 0, stream>>>(
      f_bonds, 147, nullptr, nullptr, nullptr, nullptr, Wi_b,
      nullptr, nullptr, inp_b, nullptr, nullptr);
  // base = f_atoms @ W_o1^T + b_o (pre-relu, bf16) ; d0 = relu(base) f32
  gemm6<0, 1, 160, 0, 4><<<dim3(NA / 64), blk, 0, stream>>>(
      f_atoms, 133, nullptr, nullptr, nullptr, nullptr, Wo1_b,
      nullptr, b_o, base_b, d0, nullptr);

  u16* S = inp_b;
  u16* pms[2] = {P0, P1};
  float* douts[3] = {d1, d2, dfin};
  for (int d = 0; d < 3; ++d) {
    if (d < 2) {
      // d_{d+1} = relu(base + (gather-sum) @ W_o2^T); amsg written as side-out
      gemm6<3, 3, 256, 1, 4><<<dim3(NA / 64), blk, 0, stream>>>(
          nullptr, 0, S, nullptr, a2b, nullptr, Wo2_b,
          base_b, nullptr, nullptr, douts[d], amsg);
      // S' = inp + (amsg[b2a] - relu(S[b2revb])) @ W_h^T  (gather fused)
      gemm6<2, 2, 256, 0, 3><<<dim3(NB / 64), blk, 0, stream>>>(
          nullptr, 0, amsg, S, b2a, b2revb, Wh_b,
          inp_b, nullptr, pms[d], nullptr, nullptr);
      S = pms[d];
    } else {
      gemm6<3, 3, 256, 0, 4><<<dim3(NA / 64), blk, 0, stream>>>(
          nullptr, 0, S, nullptr, a2b, nullptr, Wo2_b,
          base_b, nullptr, nullptr, douts[d], nullptr);
    }
  }
  mol_mean<<<dim3(4000), blk, 0, stream>>>(dfin, mol);
}